// Round 1
// baseline (1463.382 us; speedup 1.0000x reference)
//
#include <hip/hip_runtime.h>
#include <cmath>

#define N_NODES 20000
#define FF 78
#define F3 234   // 3*78
#define F4 312   // 4*78
#define NRBF 20
#define CUTOFF 21.0f
#define NL 3
#define PI_F 3.14159265358979323846f
#define EPS_F 1e-15f

// ---------------- init: copy H, zero V_A, zero counts/cursor ----------------
__global__ void k_init(const float* __restrict__ Hin, float* __restrict__ Hcur,
                       float* __restrict__ VA, int* __restrict__ counts, int* __restrict__ cursor)
{
    int idx = blockIdx.x * blockDim.x + threadIdx.x;
    int stride = gridDim.x * blockDim.x;
    for (int i = idx; i < N_NODES * F3; i += stride) {
        VA[i] = 0.f;
        if (i < N_NODES * FF) Hcur[i] = Hin[i];
        if (i < N_NODES) { counts[i] = 0; cursor[i] = 0; }
    }
}

// ---------------- edge geometry + active-edge degree count ----------------
__global__ void k_geo(const float* __restrict__ xyz, const int* __restrict__ nbr,
                      float4* __restrict__ geo, int* __restrict__ counts, int E)
{
    int e = blockIdx.x * blockDim.x + threadIdx.x;
    if (e >= E) return;
    int i = nbr[2 * e], j = nbr[2 * e + 1];
    float rx = xyz[3 * j]     - xyz[3 * i];
    float ry = xyz[3 * j + 1] - xyz[3 * i + 1];
    float rz = xyz[3 * j + 2] - xyz[3 * i + 2];
    // reference: sqrt((r^2 + EPS).sum(-1)) = sqrt(|r|^2 + 3*EPS)
    float d = sqrtf(rx * rx + ry * ry + rz * rz + 3.0f * EPS_F);
    geo[e] = make_float4(rx / d, ry / d, rz / d, d);
    if (d < CUTOFF) atomicAdd(&counts[i], 1);   // env==0 edges contribute exactly nothing
}

// ---------------- exclusive scan of counts -> row_start (single block) ----------------
__global__ void k_scan(const int* __restrict__ counts, int* __restrict__ row_start, int n)
{
    __shared__ int s[1024];
    __shared__ int base_s;
    int t = threadIdx.x;
    if (t == 0) base_s = 0;
    __syncthreads();
    int nch = (n + 1023) >> 10;
    for (int ch = 0; ch < nch; ++ch) {
        int i = (ch << 10) + t;
        int v = (i < n) ? counts[i] : 0;
        s[t] = v;
        __syncthreads();
        for (int off = 1; off < 1024; off <<= 1) {
            int add = (t >= off) ? s[t - off] : 0;
            __syncthreads();
            s[t] += add;
            __syncthreads();
        }
        if (i < n) row_start[i] = base_s + s[t] - v;   // exclusive
        int tot = s[1023];
        __syncthreads();
        if (t == 0) base_s += tot;
        __syncthreads();
    }
    if (t == 0) row_start[n] = base_s;
}

// ---------------- fill CSR edge lists (active edges only) ----------------
__global__ void k_fill(const float4* __restrict__ geo, const int* __restrict__ nbr,
                       const int* __restrict__ row_start, int* __restrict__ cursor,
                       int* __restrict__ edge_idx, int E)
{
    int e = blockIdx.x * blockDim.x + threadIdx.x;
    if (e >= E) return;
    if (geo[e].w < CUTOFF) {
        int i = nbr[2 * e];
        int pos = row_start[i] + atomicAdd(&cursor[i], 1);
        edge_idx[pos] = e;
    }
}

// ---------------- generic fused GEMM: Y = act([X1|X2] @ W + b) ----------------
// block: (blockDim.x = NC-ish, blockDim.y), R = blockDim.y*RS rows per block
template<int R, int RS, int ACT>   // ACT: 0 none, 1 silu, 2 relu
__global__ void k_gemm(const float* __restrict__ X1, int K1,
                       const float* __restrict__ X2, int K2,
                       const float* __restrict__ W, const float* __restrict__ B,
                       float* __restrict__ Y, int NC, int nrows)
{
    const int K = K1 + K2;
    __shared__ float sX[156 * 16];   // max K=156, max R=16
    const int r0 = blockIdx.x * R;
    const int tid = threadIdx.y * blockDim.x + threadIdx.x;
    const int nth = blockDim.x * blockDim.y;
    for (int idx = tid; idx < R * K; idx += nth) {
        int r = idx / K, k = idx - r * K;
        int row = r0 + r;
        float v = 0.f;
        if (row < nrows) v = (k < K1) ? X1[(size_t)row * K1 + k]
                                      : X2[(size_t)row * K2 + (k - K1)];
        sX[k * R + r] = v;           // [K][R] so the k-loop reads are broadcasts
    }
    __syncthreads();
    const int rg = threadIdx.y * RS;
    for (int c = threadIdx.x; c < NC; c += blockDim.x) {
        float acc[RS];
        #pragma unroll
        for (int q = 0; q < RS; ++q) acc[q] = 0.f;
        for (int k = 0; k < K; ++k) {
            const float w = W[(size_t)k * NC + c];
            #pragma unroll
            for (int q = 0; q < RS; ++q) acc[q] += w * sX[k * R + rg + q];
        }
        const float bb = B[c];
        #pragma unroll
        for (int q = 0; q < RS; ++q) {
            int row = r0 + rg + q;
            if (row < nrows) {
                float y = acc[q] + bb;
                if (ACT == 1) y = y / (1.f + expf(-y));      // silu
                else if (ACT == 2) y = fmaxf(y, 0.f);        // relu
                Y[(size_t)row * NC + c] = y;
            }
        }
    }
}

// ---------------- node-centric message pass (no atomics) ----------------
// one block per node i; thread c owns channel c of inv = phi[j]*w_s
__global__ __launch_bounds__(320)
void k_message(const float* __restrict__ phi, const float* __restrict__ Vold,
               float* __restrict__ Vnew, float* __restrict__ Hcur,
               const float4* __restrict__ geo, const int* __restrict__ row_start,
               const int* __restrict__ edge_idx, const int* __restrict__ nbr,
               const float* __restrict__ rbfw, const float* __restrict__ rbfb)
{
    const int i = blockIdx.x;
    const int t = threadIdx.x;
    __shared__ float s_vi[F3];
    __shared__ float s_rbf[NRBF];
    __shared__ float s_env;
    __shared__ float s_acc[F3];

    float wcol[NRBF];                 // rbf_w column for this channel, in registers
    float wb = 0.f;
    if (t < F4) {
        wb = rbfb[t];
        #pragma unroll
        for (int k = 0; k < NRBF; ++k) wcol[k] = rbfw[k * F4 + t];
    }
    for (int k = t; k < F3; k += 320) s_vi[k] = Vold[(size_t)i * F3 + k];
    __syncthreads();

    const int e0 = row_start[i], e1 = row_start[i + 1];
    float accH = 0.f, a0 = 0.f, a1 = 0.f, a2 = 0.f;

    for (int e = e0; e < e1; ++e) {
        const int eidx = edge_idx[e];
        const int j = nbr[2 * eidx + 1];
        const float4 g = geo[eidx];          // block-uniform load
        if (t < NRBF) {
            float d = g.w;
            s_rbf[t] = sinf((float)(t + 1) * (PI_F / CUTOFF) * d) / d;
        } else if (t == NRBF) {
            s_env = 0.5f * (cosf(PI_F * g.w / CUTOFF) + 1.0f);
        }
        __syncthreads();
        if (t < F4) {
            float w = wb;
            #pragma unroll
            for (int k = 0; k < NRBF; ++k) w += s_rbf[k] * wcol[k];
            w *= s_env;
            const float inv = phi[(size_t)j * F4 + t] * w;
            if (t < FF) {
                accH += inv;                                   // s0 -> H
            } else if (t < 2 * FF) {
                const int f = t - FF;                          // s1 * vj
                const float* vj = &Vold[(size_t)j * F3 + f * 3];
                a0 += inv * vj[0]; a1 += inv * vj[1]; a2 += inv * vj[2];
            } else if (t < 3 * FF) {
                a0 += inv * g.x; a1 += inv * g.y; a2 += inv * g.z;   // s2 * unit
            } else {
                const int f = t - 3 * FF;                      // s3 * cross(vi, vj)
                const float* vj = &Vold[(size_t)j * F3 + f * 3];
                const float vix = s_vi[f * 3], viy = s_vi[f * 3 + 1], viz = s_vi[f * 3 + 2];
                const float vjx = vj[0], vjy = vj[1], vjz = vj[2];
                a0 += inv * (viy * vjz - viz * vjy);
                a1 += inv * (viz * vjx - vix * vjz);
                a2 += inv * (vix * vjy - viy * vjx);
            }
        }
        __syncthreads();
    }

    // merge the three vector groups via LDS
    if (t >= FF && t < 2 * FF)  { int f = t - FF;     s_acc[f*3] = a0;  s_acc[f*3+1] = a1;  s_acc[f*3+2] = a2; }
    __syncthreads();
    if (t >= 2*FF && t < 3*FF)  { int f = t - 2*FF;   s_acc[f*3] += a0; s_acc[f*3+1] += a1; s_acc[f*3+2] += a2; }
    __syncthreads();
    if (t >= 3*FF && t < F4)    { int f = t - 3*FF;   s_acc[f*3] += a0; s_acc[f*3+1] += a1; s_acc[f*3+2] += a2; }
    __syncthreads();

    if (t < FF) Hcur[(size_t)i * FF + t] += accH;
    for (int k = t; k < F3; k += 320) Vnew[(size_t)i * F3 + k] = s_vi[k] + s_acc[k];
}

// ---------------- u_v / v_v einsums + v_norm ----------------
__global__ __launch_bounds__(256)
void k_upd_uv(const float* __restrict__ V, const float* __restrict__ wu, const float* __restrict__ wv,
              float* __restrict__ u_v, float* __restrict__ v_v, float* __restrict__ vnorm)
{
    const int n = blockIdx.x, t = threadIdx.x;
    __shared__ float sV[F3], sVV[F3];
    if (t < F3) sV[t] = V[(size_t)n * F3 + t];
    __syncthreads();
    if (t < F3) {
        const int g = t / 3, c = t - g * 3;
        float u = 0.f, v = 0.f;
        for (int f = 0; f < FF; ++f) {
            const float x = sV[f * 3 + c];
            u += x * wu[f * FF + g];
            v += x * wv[f * FF + g];
        }
        u_v[(size_t)n * F3 + t] = u;
        v_v[(size_t)n * F3 + t] = v;
        sVV[t] = v;
    }
    __syncthreads();
    if (t < FF) {
        const float a = sVV[t*3], b = sVV[t*3+1], c = sVV[t*3+2];
        vnorm[(size_t)n * FF + t] = sqrtf(a*a + b*b + c*c + EPS_F);
    }
}

// ---------------- apply gated update ----------------
__global__ void k_upd_apply(float* __restrict__ H, float* __restrict__ V,
                            const float* __restrict__ u_v, const float* __restrict__ v_v,
                            const float* __restrict__ a)
{
    int idx = blockIdx.x * blockDim.x + threadIdx.x;
    if (idx >= N_NODES * FF) return;
    int n = idx / FF, g = idx - n * FF;
    size_t b3 = (size_t)n * F3 + g * 3;
    float u0 = u_v[b3], u1 = u_v[b3+1], u2 = u_v[b3+2];
    float v0 = v_v[b3], v1 = v_v[b3+1], v2 = v_v[b3+2];
    float dot = u0*v0 + u1*v1 + u2*v2;
    size_t ab = (size_t)n * F3;
    float avv = a[ab + g], asv = a[ab + FF + g], ass = a[ab + 2*FF + g];
    H[idx] += asv * dot + ass;
    V[b3]   += avv * u0;
    V[b3+1] += avv * u1;
    V[b3+2] += avv * u2;
}

// ---------------- copy H to output ----------------
__global__ void k_copyH(const float* __restrict__ src, float* __restrict__ dst)
{
    int idx = blockIdx.x * blockDim.x + threadIdx.x;
    if (idx < N_NODES * FF) dst[idx] = src[idx];
}

// ---------------- decoder: Vs=relu(V.sum(-1)); 78->39 relu; 39->39 ----------------
__global__ __launch_bounds__(128)
void k_decode(const float* __restrict__ V, const float* __restrict__ w1, const float* __restrict__ b1,
              const float* __restrict__ w2, const float* __restrict__ b2, float* __restrict__ out)
{
    const int n = blockIdx.x, t = threadIdx.x;
    __shared__ float sx[FF];
    __shared__ float sh[39];
    if (t < FF) {
        size_t b = (size_t)n * F3 + t * 3;
        float x = V[b] + V[b+1] + V[b+2];
        sx[t] = fmaxf(x, 0.f);
    }
    __syncthreads();
    if (t < 39) {
        float h = b1[t];
        for (int g = 0; g < FF; ++g) h += sx[g] * w1[g * 39 + t];
        sh[t] = fmaxf(h, 0.f);
    }
    __syncthreads();
    if (t < 39) {
        float o = b2[t];
        for (int m = 0; m < 39; ++m) o += sh[m] * w2[m * 39 + t];
        out[(size_t)n * 39 + t] = o;
    }
}

extern "C" void kernel_launch(void* const* d_in, const int* in_sizes, int n_in,
                              void* d_out, int out_size, void* d_ws, size_t ws_size,
                              hipStream_t stream)
{
    const float* xyz    = (const float*)d_in[0];
    const int*   nbr    = (const int*)  d_in[1];
    // d_in[2] = mapping (unused by reference)
    const float* Hin    = (const float*)d_in[3];
    const float* msg_w1 = (const float*)d_in[4];
    const float* msg_b1 = (const float*)d_in[5];
    const float* msg_w2 = (const float*)d_in[6];
    const float* msg_b2 = (const float*)d_in[7];
    const float* rbf_w  = (const float*)d_in[8];
    const float* rbf_b  = (const float*)d_in[9];
    const float* upd_wu = (const float*)d_in[10];
    const float* upd_wv = (const float*)d_in[11];
    const float* upd_w1 = (const float*)d_in[12];
    const float* upd_b1 = (const float*)d_in[13];
    const float* upd_w2 = (const float*)d_in[14];
    const float* upd_b2 = (const float*)d_in[15];
    const float* dw1    = (const float*)d_in[16];
    const float* db1    = (const float*)d_in[17];
    const float* dw2    = (const float*)d_in[18];
    const float* db2    = (const float*)d_in[19];
    const int E = in_sizes[1] / 2;

    // workspace layout (fp32 elements) ~125 MB total
    float* ws = (float*)d_ws;
    size_t off = 0;
    float* Hcur  = ws + off; off += (size_t)N_NODES * FF;
    float* VA    = ws + off; off += (size_t)N_NODES * F3;
    float* VB    = ws + off; off += (size_t)N_NODES * F3;
    float* phi   = ws + off; off += (size_t)N_NODES * F4;   // reused as 'a' later
    float* hid   = ws + off; off += (size_t)N_NODES * FF;
    float* u_v   = ws + off; off += (size_t)N_NODES * F3;
    float* v_v   = ws + off; off += (size_t)N_NODES * F3;
    float* vnorm = ws + off; off += (size_t)N_NODES * FF;
    float4* geo  = (float4*)(ws + off); off += (size_t)E * 4;
    int* ibase     = (int*)(ws + off);
    int* row_start = ibase;                       // N+1
    int* counts    = row_start + (N_NODES + 1);   // N
    int* cursor    = counts + N_NODES;            // N
    int* edge_idx  = cursor + N_NODES;            // E

    k_init<<<dim3((N_NODES * F3 + 255) / 256), dim3(256), 0, stream>>>(Hin, Hcur, VA, counts, cursor);
    k_geo<<<dim3((E + 255) / 256), dim3(256), 0, stream>>>(xyz, nbr, geo, counts, E);
    k_scan<<<dim3(1), dim3(1024), 0, stream>>>(counts, row_start, N_NODES);
    k_fill<<<dim3((E + 255) / 256), dim3(256), 0, stream>>>(geo, nbr, row_start, cursor, edge_idx, E);

    float* Vold = VA;
    float* Vnew = VB;
    for (int l = 0; l < NL; ++l) {
        // phi = silu(H@w1+b1)@w2+b2
        k_gemm<16, 4, 1><<<dim3((N_NODES + 15) / 16), dim3(78, 4), 0, stream>>>(
            Hcur, 78, nullptr, 0, msg_w1 + (size_t)l * 78 * 78, msg_b1 + (size_t)l * 78, hid, 78, N_NODES);
        k_gemm<8, 8, 0><<<dim3((N_NODES + 7) / 8), dim3(312, 1), 0, stream>>>(
            hid, 78, nullptr, 0, msg_w2 + (size_t)l * 78 * 312, msg_b2 + (size_t)l * 312, phi, 312, N_NODES);
        // message pass: H += seg_sum(s0), Vnew = Vold + seg_sum(dv)
        k_message<<<dim3(N_NODES), dim3(320), 0, stream>>>(
            phi, Vold, Vnew, Hcur, geo, row_start, edge_idx, nbr,
            rbf_w + (size_t)l * NRBF * F4, rbf_b + (size_t)l * F4);
        // u_v, v_v, v_norm
        k_upd_uv<<<dim3(N_NODES), dim3(256), 0, stream>>>(
            Vnew, upd_wu + (size_t)l * 78 * 78, upd_wv + (size_t)l * 78 * 78, u_v, v_v, vnorm);
        // a = silu([H|vnorm]@uw1+ub1)@uw2+ub2   (writes into phi buffer)
        k_gemm<16, 4, 1><<<dim3((N_NODES + 15) / 16), dim3(78, 4), 0, stream>>>(
            Hcur, 78, vnorm, 78, upd_w1 + (size_t)l * 156 * 78, upd_b1 + (size_t)l * 78, hid, 78, N_NODES);
        k_gemm<8, 8, 0><<<dim3((N_NODES + 7) / 8), dim3(234, 1), 0, stream>>>(
            hid, 78, nullptr, 0, upd_w2 + (size_t)l * 78 * 234, upd_b2 + (size_t)l * 234, phi, 234, N_NODES);
        // H += a_sv*(u.v) + a_ss ; V += a_vv*u
        k_upd_apply<<<dim3((N_NODES * FF + 255) / 256), dim3(256), 0, stream>>>(Hcur, Vnew, u_v, v_v, phi);
        float* tmp = Vold; Vold = Vnew; Vnew = tmp;
    }

    float* dout = (float*)d_out;
    k_copyH<<<dim3((N_NODES * FF + 255) / 256), dim3(256), 0, stream>>>(Hcur, dout);
    k_decode<<<dim3(N_NODES), dim3(128), 0, stream>>>(Vold, dw1, db1, dw2, db2, dout + (size_t)N_NODES * FF);
}

// Round 2
// 930.119 us; speedup vs baseline: 1.5733x; 1.5733x over previous
//
#include <hip/hip_runtime.h>
#include <cmath>

#define N_NODES 20000
#define FF 78
#define F3 234   // 3*78
#define F4 312   // 4*78
#define NRBF 20
#define CUTOFF 21.0f
#define NL 3
#define PI_F 3.14159265358979323846f
#define EPS_F 1e-15f
#define REC_STRIDE 24

// ---------------- init: copy H, zero V_A, zero counts/cursor ----------------
__global__ void k_init(const float* __restrict__ Hin, float* __restrict__ Hcur,
                       float* __restrict__ VA, int* __restrict__ counts, int* __restrict__ cursor)
{
    int idx = blockIdx.x * blockDim.x + threadIdx.x;
    int stride = gridDim.x * blockDim.x;
    for (int i = idx; i < N_NODES * F3; i += stride) {
        VA[i] = 0.f;
        if (i < N_NODES * FF) Hcur[i] = Hin[i];
        if (i < N_NODES) { counts[i] = 0; cursor[i] = 0; }
    }
}

// ---------------- edge geometry + active-edge degree count ----------------
__global__ void k_geo(const float* __restrict__ xyz, const int* __restrict__ nbr,
                      float4* __restrict__ geo, int* __restrict__ counts, int E)
{
    int e = blockIdx.x * blockDim.x + threadIdx.x;
    if (e >= E) return;
    int i = nbr[2 * e], j = nbr[2 * e + 1];
    float rx = xyz[3 * j]     - xyz[3 * i];
    float ry = xyz[3 * j + 1] - xyz[3 * i + 1];
    float rz = xyz[3 * j + 2] - xyz[3 * i + 2];
    float d = sqrtf(rx * rx + ry * ry + rz * rz + 3.0f * EPS_F);
    geo[e] = make_float4(rx / d, ry / d, rz / d, d);
    if (d < CUTOFF) atomicAdd(&counts[i], 1);   // env==0 edges contribute exactly nothing
}

// ---------------- exclusive scan of counts -> row_start (single block) ----------------
__global__ void k_scan(const int* __restrict__ counts, int* __restrict__ row_start, int n)
{
    __shared__ int s[1024];
    __shared__ int base_s;
    int t = threadIdx.x;
    if (t == 0) base_s = 0;
    __syncthreads();
    int nch = (n + 1023) >> 10;
    for (int ch = 0; ch < nch; ++ch) {
        int i = (ch << 10) + t;
        int v = (i < n) ? counts[i] : 0;
        s[t] = v;
        __syncthreads();
        for (int off = 1; off < 1024; off <<= 1) {
            int add = (t >= off) ? s[t - off] : 0;
            __syncthreads();
            s[t] += add;
            __syncthreads();
        }
        if (i < n) row_start[i] = base_s + s[t] - v;   // exclusive
        int tot = s[1023];
        __syncthreads();
        if (t == 0) base_s += tot;
        __syncthreads();
    }
    if (t == 0) row_start[n] = base_s;
}

// ---------------- fill CSR edge lists (active edges only) ----------------
__global__ void k_fill(const float4* __restrict__ geo, const int* __restrict__ nbr,
                       const int* __restrict__ row_start, int* __restrict__ cursor,
                       int* __restrict__ edge_idx, int E)
{
    int e = blockIdx.x * blockDim.x + threadIdx.x;
    if (e >= E) return;
    if (geo[e].w < CUTOFF) {
        int i = nbr[2 * e];
        int pos = row_start[i] + atomicAdd(&cursor[i], 1);
        edge_idx[pos] = e;
    }
}

// ---------------- per-active-edge record: [rbf_k*env (20), env, unit (3)] ----------------
__global__ void k_edgerec(const float4* __restrict__ geo, const int* __restrict__ edge_idx,
                          const int* __restrict__ nbr, const int* __restrict__ row_start,
                          float* __restrict__ rec, int* __restrict__ jl, int E)
{
    int p = blockIdx.x * blockDim.x + threadIdx.x;
    int total = row_start[N_NODES];
    if (p >= total) return;
    int eidx = edge_idx[p];
    float4 g = geo[eidx];
    float d = g.w;
    float env = 0.5f * (cosf(PI_F * d / CUTOFF) + 1.0f);
    float* r = rec + (size_t)p * REC_STRIDE;
    #pragma unroll
    for (int k = 0; k < NRBF; ++k)
        r[k] = env * sinf((float)(k + 1) * (PI_F / CUTOFF) * d) / d;
    r[20] = env;
    r[21] = g.x; r[22] = g.y; r[23] = g.z;
    jl[p] = nbr[2 * eidx + 1];
}

// ---------------- generic fused GEMM: Y = act([X1|X2] @ W + b), R=16 rows/block ----------------
template<int RS, int CS, int ACT>   // ACT: 0 none, 1 silu
__global__ void k_gemmv(const float* __restrict__ X1, int K1,
                        const float* __restrict__ X2, int K2,
                        const float* __restrict__ W, const float* __restrict__ B,
                        float* __restrict__ Y, int NC, int nrows)
{
    constexpr int R = 16;
    const int K = K1 + K2;
    __shared__ float sX[156 * R];
    const int r0 = blockIdx.x * R;
    const int tid = threadIdx.y * blockDim.x + threadIdx.x;
    const int nth = blockDim.x * blockDim.y;
    for (int idx = tid; idx < R * K; idx += nth) {
        int r = idx / K, k = idx - r * K;
        int row = r0 + r;
        float v = 0.f;
        if (row < nrows) v = (k < K1) ? X1[(size_t)row * K1 + k]
                                      : X2[(size_t)row * K2 + (k - K1)];
        sX[k * R + r] = v;
    }
    __syncthreads();
    const int rg = threadIdx.y * RS;
    const int c0 = threadIdx.x * CS;
    float acc[RS][CS];
    #pragma unroll
    for (int q = 0; q < RS; ++q)
        #pragma unroll
        for (int cc = 0; cc < CS; ++cc) acc[q][cc] = 0.f;
    for (int k = 0; k < K; ++k) {
        float xv[RS];
        #pragma unroll
        for (int q = 0; q < RS; ++q) xv[q] = sX[k * R + rg + q];
        float wv[CS];
        #pragma unroll
        for (int cc = 0; cc < CS; ++cc) wv[cc] = W[(size_t)k * NC + c0 + cc];
        #pragma unroll
        for (int q = 0; q < RS; ++q)
            #pragma unroll
            for (int cc = 0; cc < CS; ++cc) acc[q][cc] += xv[q] * wv[cc];
    }
    #pragma unroll
    for (int q = 0; q < RS; ++q) {
        int row = r0 + rg + q;
        if (row < nrows) {
            #pragma unroll
            for (int cc = 0; cc < CS; ++cc) {
                float y = acc[q][cc] + B[c0 + cc];
                if (ACT == 1) y = y / (1.f + expf(-y));      // silu
                Y[(size_t)row * NC + c0 + cc] = y;
            }
        }
    }
}

// ---------------- node-centric message pass: barrier-free edge loop ----------------
__global__ __launch_bounds__(320)
void k_message(const float* __restrict__ phi, const float* __restrict__ Vold,
               float* __restrict__ Vnew, float* __restrict__ Hcur,
               const float* __restrict__ rec, const int* __restrict__ jl,
               const int* __restrict__ row_start,
               const float* __restrict__ rbfw, const float* __restrict__ rbfb)
{
    const int i = blockIdx.x;
    const int t = threadIdx.x;
    __shared__ float s_vi[F3];
    __shared__ float s_acc[F3];

    float wcol[NRBF];
    #pragma unroll
    for (int k = 0; k < NRBF; ++k) wcol[k] = 0.f;
    float wb = 0.f;
    if (t < F4) {
        wb = rbfb[t];
        #pragma unroll
        for (int k = 0; k < NRBF; ++k) wcol[k] = rbfw[k * F4 + t];
    }
    for (int k = t; k < F3; k += 320) s_vi[k] = Vold[(size_t)i * F3 + k];
    __syncthreads();

    const int e0 = row_start[i], e1 = row_start[i + 1];
    float accH = 0.f, a0 = 0.f, a1 = 0.f, a2 = 0.f;

    for (int e = e0; e < e1; ++e) {
        const float* __restrict__ r = rec + (size_t)e * REC_STRIDE;
        const int j = jl[e];
        float w = wb * r[20];
        #pragma unroll
        for (int k = 0; k < NRBF; ++k) w += r[k] * wcol[k];
        if (t < FF) {
            accH += phi[(size_t)j * F4 + t] * w;               // s0 -> H
        } else if (t < 2 * FF) {
            const float inv = phi[(size_t)j * F4 + t] * w;     // s1 * vj
            const float* vj = &Vold[(size_t)j * F3 + (t - FF) * 3];
            a0 += inv * vj[0]; a1 += inv * vj[1]; a2 += inv * vj[2];
        } else if (t < 3 * FF) {
            const float inv = phi[(size_t)j * F4 + t] * w;     // s2 * unit
            a0 += inv * r[21]; a1 += inv * r[22]; a2 += inv * r[23];
        } else if (t < F4) {
            const float inv = phi[(size_t)j * F4 + t] * w;     // s3 * cross(vi, vj)
            const int f = t - 3 * FF;
            const float* vj = &Vold[(size_t)j * F3 + f * 3];
            const float vix = s_vi[f * 3], viy = s_vi[f * 3 + 1], viz = s_vi[f * 3 + 2];
            a0 += inv * (viy * vj[2] - viz * vj[1]);
            a1 += inv * (viz * vj[0] - vix * vj[2]);
            a2 += inv * (vix * vj[1] - viy * vj[0]);
        }
    }

    // merge the three vector groups via LDS
    if (t >= FF && t < 2 * FF)  { int f = t - FF;     s_acc[f*3] = a0;  s_acc[f*3+1] = a1;  s_acc[f*3+2] = a2; }
    __syncthreads();
    if (t >= 2*FF && t < 3*FF)  { int f = t - 2*FF;   s_acc[f*3] += a0; s_acc[f*3+1] += a1; s_acc[f*3+2] += a2; }
    __syncthreads();
    if (t >= 3*FF && t < F4)    { int f = t - 3*FF;   s_acc[f*3] += a0; s_acc[f*3+1] += a1; s_acc[f*3+2] += a2; }
    __syncthreads();

    if (t < FF) Hcur[(size_t)i * FF + t] += accH;
    for (int k = t; k < F3; k += 320) Vnew[(size_t)i * F3 + k] = s_vi[k] + s_acc[k];
}

// ---------------- u_v / v_v einsums + v_norm, 8 nodes/block ----------------
#define UV_RN 8
__global__ __launch_bounds__(256)
void k_upd_uv(const float* __restrict__ V, const float* __restrict__ wu, const float* __restrict__ wv,
              float* __restrict__ u_v, float* __restrict__ v_v, float* __restrict__ vnorm)
{
    const int n0 = blockIdx.x * UV_RN;
    const int t = threadIdx.x;
    __shared__ float sV[F3 * UV_RN];   // [k][n]
    for (int idx = t; idx < F3 * UV_RN; idx += 256) {
        int n = idx / F3, k = idx - n * F3;
        sV[k * UV_RN + n] = V[(size_t)(n0 + n) * F3 + k];
    }
    __syncthreads();
    float au[UV_RN], av[UV_RN];
    #pragma unroll
    for (int n = 0; n < UV_RN; ++n) { au[n] = 0.f; av[n] = 0.f; }
    if (t < F3) {
        const int g = t / 3, c = t - g * 3;
        for (int f = 0; f < FF; ++f) {
            const float wuv = wu[f * FF + g];
            const float wvv = wv[f * FF + g];
            const float* xs = &sV[(f * 3 + c) * UV_RN];
            #pragma unroll
            for (int n = 0; n < UV_RN; ++n) {
                const float x = xs[n];
                au[n] += x * wuv; av[n] += x * wvv;
            }
        }
        #pragma unroll
        for (int n = 0; n < UV_RN; ++n) {
            u_v[(size_t)(n0 + n) * F3 + t] = au[n];
            v_v[(size_t)(n0 + n) * F3 + t] = av[n];
        }
    }
    __syncthreads();
    if (t < F3) {
        #pragma unroll
        for (int n = 0; n < UV_RN; ++n) sV[t * UV_RN + n] = av[n];
    }
    __syncthreads();
    for (int idx = t; idx < FF * UV_RN; idx += 256) {
        int g = idx / UV_RN, n = idx - g * UV_RN;
        float a = sV[(g * 3 + 0) * UV_RN + n];
        float b = sV[(g * 3 + 1) * UV_RN + n];
        float c = sV[(g * 3 + 2) * UV_RN + n];
        vnorm[(size_t)(n0 + n) * FF + g] = sqrtf(a * a + b * b + c * c + EPS_F);
    }
}

// ---------------- apply gated update ----------------
__global__ void k_upd_apply(float* __restrict__ H, float* __restrict__ V,
                            const float* __restrict__ u_v, const float* __restrict__ v_v,
                            const float* __restrict__ a)
{
    int idx = blockIdx.x * blockDim.x + threadIdx.x;
    if (idx >= N_NODES * FF) return;
    int n = idx / FF, g = idx - n * FF;
    size_t b3 = (size_t)n * F3 + g * 3;
    float u0 = u_v[b3], u1 = u_v[b3+1], u2 = u_v[b3+2];
    float v0 = v_v[b3], v1 = v_v[b3+1], v2 = v_v[b3+2];
    float dot = u0*v0 + u1*v1 + u2*v2;
    size_t ab = (size_t)n * F3;
    float avv = a[ab + g], asv = a[ab + FF + g], ass = a[ab + 2*FF + g];
    H[idx] += asv * dot + ass;
    V[b3]   += avv * u0;
    V[b3+1] += avv * u1;
    V[b3+2] += avv * u2;
}

// ---------------- copy H to output ----------------
__global__ void k_copyH(const float* __restrict__ src, float* __restrict__ dst)
{
    int idx = blockIdx.x * blockDim.x + threadIdx.x;
    if (idx < N_NODES * FF) dst[idx] = src[idx];
}

// ---------------- decoder ----------------
__global__ __launch_bounds__(128)
void k_decode(const float* __restrict__ V, const float* __restrict__ w1, const float* __restrict__ b1,
              const float* __restrict__ w2, const float* __restrict__ b2, float* __restrict__ out)
{
    const int n = blockIdx.x, t = threadIdx.x;
    __shared__ float sx[FF];
    __shared__ float sh[39];
    if (t < FF) {
        size_t b = (size_t)n * F3 + t * 3;
        float x = V[b] + V[b+1] + V[b+2];
        sx[t] = fmaxf(x, 0.f);
    }
    __syncthreads();
    if (t < 39) {
        float h = b1[t];
        for (int g = 0; g < FF; ++g) h += sx[g] * w1[g * 39 + t];
        sh[t] = fmaxf(h, 0.f);
    }
    __syncthreads();
    if (t < 39) {
        float o = b2[t];
        for (int m = 0; m < 39; ++m) o += sh[m] * w2[m * 39 + t];
        out[(size_t)n * 39 + t] = o;
    }
}

extern "C" void kernel_launch(void* const* d_in, const int* in_sizes, int n_in,
                              void* d_out, int out_size, void* d_ws, size_t ws_size,
                              hipStream_t stream)
{
    const float* xyz    = (const float*)d_in[0];
    const int*   nbr    = (const int*)  d_in[1];
    const float* Hin    = (const float*)d_in[3];
    const float* msg_w1 = (const float*)d_in[4];
    const float* msg_b1 = (const float*)d_in[5];
    const float* msg_w2 = (const float*)d_in[6];
    const float* msg_b2 = (const float*)d_in[7];
    const float* rbf_w  = (const float*)d_in[8];
    const float* rbf_b  = (const float*)d_in[9];
    const float* upd_wu = (const float*)d_in[10];
    const float* upd_wv = (const float*)d_in[11];
    const float* upd_w1 = (const float*)d_in[12];
    const float* upd_b1 = (const float*)d_in[13];
    const float* upd_w2 = (const float*)d_in[14];
    const float* upd_b2 = (const float*)d_in[15];
    const float* dw1    = (const float*)d_in[16];
    const float* db1    = (const float*)d_in[17];
    const float* dw2    = (const float*)d_in[18];
    const float* db2    = (const float*)d_in[19];
    const int E = in_sizes[1] / 2;

    float* ws = (float*)d_ws;
    size_t off = 0;
    float* Hcur  = ws + off; off += (size_t)N_NODES * FF;
    float* VA    = ws + off; off += (size_t)N_NODES * F3;
    float* VB    = ws + off; off += (size_t)N_NODES * F3;
    float* phi   = ws + off; off += (size_t)N_NODES * F4;   // reused as 'a' later
    float* hid   = ws + off; off += (size_t)N_NODES * FF;
    float* u_v   = ws + off; off += (size_t)N_NODES * F3;
    float* v_v   = ws + off; off += (size_t)N_NODES * F3;
    float* vnorm = ws + off; off += (size_t)N_NODES * FF;
    float4* geo  = (float4*)(ws + off); off += (size_t)E * 4;
    float* rec   = ws + off; off += (size_t)E * REC_STRIDE;
    int* ibase     = (int*)(ws + off);
    int* row_start = ibase;                       // N+1
    int* counts    = row_start + (N_NODES + 1);   // N
    int* cursor    = counts + N_NODES;            // N
    int* edge_idx  = cursor + N_NODES;            // E
    int* jl        = edge_idx + E;                // E

    k_init<<<dim3((N_NODES * F3 + 255) / 256), dim3(256), 0, stream>>>(Hin, Hcur, VA, counts, cursor);
    k_geo<<<dim3((E + 255) / 256), dim3(256), 0, stream>>>(xyz, nbr, geo, counts, E);
    k_scan<<<dim3(1), dim3(1024), 0, stream>>>(counts, row_start, N_NODES);
    k_fill<<<dim3((E + 255) / 256), dim3(256), 0, stream>>>(geo, nbr, row_start, cursor, edge_idx, E);
    k_edgerec<<<dim3((E + 255) / 256), dim3(256), 0, stream>>>(geo, edge_idx, nbr, row_start, rec, jl, E);

    float* Vold = VA;
    float* Vnew = VB;
    for (int l = 0; l < NL; ++l) {
        // phi = silu(H@w1+b1)@w2+b2
        k_gemmv<4, 1, 1><<<dim3((N_NODES + 15) / 16), dim3(78, 4), 0, stream>>>(
            Hcur, 78, nullptr, 0, msg_w1 + (size_t)l * 78 * 78, msg_b1 + (size_t)l * 78, hid, 78, N_NODES);
        k_gemmv<4, 4, 0><<<dim3((N_NODES + 15) / 16), dim3(78, 4), 0, stream>>>(
            hid, 78, nullptr, 0, msg_w2 + (size_t)l * 78 * 312, msg_b2 + (size_t)l * 312, phi, 312, N_NODES);
        // message pass
        k_message<<<dim3(N_NODES), dim3(320), 0, stream>>>(
            phi, Vold, Vnew, Hcur, rec, jl, row_start,
            rbf_w + (size_t)l * NRBF * F4, rbf_b + (size_t)l * F4);
        // u_v, v_v, v_norm
        k_upd_uv<<<dim3(N_NODES / UV_RN), dim3(256), 0, stream>>>(
            Vnew, upd_wu + (size_t)l * 78 * 78, upd_wv + (size_t)l * 78 * 78, u_v, v_v, vnorm);
        // a = silu([H|vnorm]@uw1+ub1)@uw2+ub2   (into phi buffer)
        k_gemmv<4, 1, 1><<<dim3((N_NODES + 15) / 16), dim3(78, 4), 0, stream>>>(
            Hcur, 78, vnorm, 78, upd_w1 + (size_t)l * 156 * 78, upd_b1 + (size_t)l * 78, hid, 78, N_NODES);
        k_gemmv<4, 3, 0><<<dim3((N_NODES + 15) / 16), dim3(78, 4), 0, stream>>>(
            hid, 78, nullptr, 0, upd_w2 + (size_t)l * 78 * 234, upd_b2 + (size_t)l * 234, phi, 234, N_NODES);
        // H += a_sv*(u.v) + a_ss ; V += a_vv*u
        k_upd_apply<<<dim3((N_NODES * FF + 255) / 256), dim3(256), 0, stream>>>(Hcur, Vnew, u_v, v_v, phi);
        float* tmp = Vold; Vold = Vnew; Vnew = tmp;
    }

    float* dout = (float*)d_out;
    k_copyH<<<dim3((N_NODES * FF + 255) / 256), dim3(256), 0, stream>>>(Hcur, dout);
    k_decode<<<dim3(N_NODES), dim3(128), 0, stream>>>(Vold, dw1, db1, dw2, db2, dout + (size_t)N_NODES * FF);
}